// Round 12
// baseline (213.212 us; speedup 1.0000x reference)
//
#include <hip/hip_runtime.h>
#include <hip/hip_fp16.h>

#define N_NODES 50000
#define N_EDGES 800000
#define IN_DIM  128
#define HID     64
#define HID2    32
#define HEADS   4
#define LATENT  32
#define NEG_SLOPE 0.2f
#define SUBBINS 8
#define SUBCAP  20            // per-sub-bin capacity; lambda=2 -> P(overflow) ~ 3e-8
#define ROWSLOT (SUBBINS * SUBCAP)   // 160 ushorts = 320 B per node

#define GB1   ((N_NODES + 63) / 64)      // 782 gemm1 blocks
#define NBIN  ((N_EDGES + 255) / 256)    // 3125 binning blocks (placed FIRST)

typedef _Float16 half8v __attribute__((ext_vector_type(8)));
typedef _Float16 half4v __attribute__((ext_vector_type(4)));
typedef float    float4v __attribute__((ext_vector_type(4)));

// ---------------- workspace layout (float offsets) ----------------
#define OFF_XH1H  ((size_t)0)            //  6,400,000 (half storage)
#define OFF_XH2H  ((size_t)0)            //  3,200,000 (overlay, xh1 dead)
#define OFF_ALS2  ((size_t)8000000)      //    200,000
#define OFF_ALD2  ((size_t)8200000)      //    200,000
#define OFF_AGG1  ((size_t)8400000)      //  3,200,000
#define OFF_ALS1  ((size_t)11600000)     //    200,000
#define OFF_ALD1  ((size_t)11800000)     //    200,000
#define OFF_CUR   ((size_t)12000000)     //    400,000 ints (8 cursors/node)
#define OFF_ESRC  ((size_t)12400000)     //  4,000,000 float slots (50k x 160 ushorts)
#define OFF_W1TH  ((size_t)16400000)     //     16,384 float slots (32768 halves)
#define OFF_W2TH  ((size_t)16416384)     //      4,096 float slots (8192 halves)
// total 16,420,480 floats = 65.7 MB

#define NB_ZERO ((N_NODES * SUBBINS + 255) / 256)  // 1563

__device__ __forceinline__ float lrelu(float v) {
    return v > 0.f ? v : NEG_SLOPE * v;
}

// ---------------- K0: weight fp16 transposes + cursor zeroing (fused) ----------------
__global__ void k_prep(const float* __restrict__ W1, const float* __restrict__ W2,
                       __half* __restrict__ w1t, __half* __restrict__ w2t,
                       int* __restrict__ cur) {
    if (blockIdx.x < 160) {
        const int t = blockIdx.x * 256 + threadIdx.x;
        if (t < 32768) {
            const int k = t >> 8, n = t & 255;
            w1t[n * IN_DIM + k] = __float2half(W1[t]);
        } else {
            const int t2 = t - 32768;
            const int k = t2 >> 7, n = t2 & 127;
            w2t[n * HID + k] = __float2half(W2[t2]);
        }
    } else {
        const int i = (blockIdx.x - 160) * 256 + threadIdx.x;
        if (i < N_NODES * SUBBINS) cur[i] = 0;
    }
}

// ---------------- K1 (hybrid dispatch):
//   blocks [0, NBIN):        edge binning into 8 sub-bins/node (starts first)
//   blocks [NBIN, NBIN+GB1): xh1h = half(x @ W1) MFMA + fused als1/ald1
__global__ void k_gemm1_mfma(const float* __restrict__ x, const __half* __restrict__ w1t,
                             const float* __restrict__ as1, const float* __restrict__ ad1,
                             __half* __restrict__ xh1, float* __restrict__ als,
                             float* __restrict__ ald, const int* __restrict__ ei,
                             int* __restrict__ cur, unsigned short* __restrict__ esrc) {
    const int tid = threadIdx.x;
    if (blockIdx.x < NBIN) {
        const int e = blockIdx.x * 256 + tid;
        if (e < N_EDGES) {
            const int s = ei[e], dd = ei[N_EDGES + e];
            const int sub = e & (SUBBINS - 1);
            const int pos = atomicAdd(&cur[dd * SUBBINS + sub], 1);
            if (pos < SUBCAP)
                esrc[(size_t)dd * ROWSLOT + sub * SUBCAP + pos] = (unsigned short)s;
        }
        return;
    }
    __shared__ _Float16 xsh[64][136];
    __shared__ _Float16 wsh[64][136];
    const int m0 = (blockIdx.x - NBIN) * 64;
#pragma unroll
    for (int i = 0; i < 8; i++) {
        const int f = tid + i * 256;
        const int r = f >> 5;
        const int k = (f & 31) * 4;
        const int gr = (m0 + r < N_NODES) ? (m0 + r) : (N_NODES - 1);
        const float4 xv = *(const float4*)(x + (size_t)gr * IN_DIM + k);
        half4v hv = { (_Float16)xv.x, (_Float16)xv.y, (_Float16)xv.z, (_Float16)xv.w };
        *(half4v*)&xsh[r][k] = hv;
    }
    const int w = tid >> 6, l = tid & 63;
    const int lr = l & 15;
    const int lk = (l >> 4) * 8;
    const int rbase = m0 + w * 16 + (l >> 4) * 4;
    for (int nb = 0; nb < 4; nb++) {
        const int n0 = nb * 64;
        __syncthreads();
#pragma unroll
        for (int i = 0; i < 4; i++) {
            const int u = tid + i * 256;
            const int r = u >> 4;
            const int k = (u & 15) * 8;
            *(half8v*)&wsh[r][k] = *(const half8v*)(w1t + (size_t)(n0 + r) * IN_DIM + k);
        }
        __syncthreads();
        float4v acc0 = {0.f,0.f,0.f,0.f}, acc1 = {0.f,0.f,0.f,0.f};
        float4v acc2 = {0.f,0.f,0.f,0.f}, acc3 = {0.f,0.f,0.f,0.f};
#pragma unroll
        for (int k0 = 0; k0 < IN_DIM; k0 += 32) {
            const half8v a  = *(const half8v*)&xsh[w * 16 + lr][k0 + lk];
            const half8v b0 = *(const half8v*)&wsh[ 0 + lr][k0 + lk];
            const half8v b1 = *(const half8v*)&wsh[16 + lr][k0 + lk];
            const half8v b2 = *(const half8v*)&wsh[32 + lr][k0 + lk];
            const half8v b3 = *(const half8v*)&wsh[48 + lr][k0 + lk];
            acc0 = __builtin_amdgcn_mfma_f32_16x16x32_f16(a, b0, acc0, 0, 0, 0);
            acc1 = __builtin_amdgcn_mfma_f32_16x16x32_f16(a, b1, acc1, 0, 0, 0);
            acc2 = __builtin_amdgcn_mfma_f32_16x16x32_f16(a, b2, acc2, 0, 0, 0);
            acc3 = __builtin_amdgcn_mfma_f32_16x16x32_f16(a, b3, acc3, 0, 0, 0);
        }
        const int cbase = n0 + lr;
#pragma unroll
        for (int r = 0; r < 4; r++) {
            const int node = rbase + r;
            if (node < N_NODES) {
                __half* p = xh1 + (size_t)node * (HEADS * HID) + cbase;
                p[0]  = __float2half(acc0[r]);
                p[16] = __float2half(acc1[r]);
                p[32] = __float2half(acc2[r]);
                p[48] = __float2half(acc3[r]);
            }
        }
        const int h = nb;
        const float a0 = as1[(h << 6) + lr +  0], a1 = as1[(h << 6) + lr + 16];
        const float a2 = as1[(h << 6) + lr + 32], a3 = as1[(h << 6) + lr + 48];
        const float d0 = ad1[(h << 6) + lr +  0], d1 = ad1[(h << 6) + lr + 16];
        const float d2 = ad1[(h << 6) + lr + 32], d3 = ad1[(h << 6) + lr + 48];
#pragma unroll
        for (int r = 0; r < 4; r++) {
            float ps = acc0[r] * a0 + acc1[r] * a1 + acc2[r] * a2 + acc3[r] * a3;
            float pd = acc0[r] * d0 + acc1[r] * d1 + acc2[r] * d2 + acc3[r] * d3;
            ps += __shfl_xor(ps, 1); pd += __shfl_xor(pd, 1);
            ps += __shfl_xor(ps, 2); pd += __shfl_xor(pd, 2);
            ps += __shfl_xor(ps, 4); pd += __shfl_xor(pd, 4);
            ps += __shfl_xor(ps, 8); pd += __shfl_xor(pd, 8);
            if (lr == 0) {
                const int node = rbase + r;
                if (node < N_NODES) {
                    als[node * HEADS + h] = ps;
                    ald[node * HEADS + h] = pd;
                }
            }
        }
    }
}

// map logical edge index u in [0, deg) to physical slot via sub-bin prefix
__device__ __forceinline__ int bin_slot(int u, int p1, int p2, int p3, int p4,
                                        int p5, int p6, int p7) {
    const int b = (u >= p1) + (u >= p2) + (u >= p3) + (u >= p4) +
                  (u >= p5) + (u >= p6) + (u >= p7);
    int pb = (b >= 1) ? p1 : 0;
    pb = (b >= 2) ? p2 : pb;
    pb = (b >= 3) ? p3 : pb;
    pb = (b >= 4) ? p4 : pb;
    pb = (b >= 5) ? p5 : pb;
    pb = (b >= 6) ? p6 : pb;
    pb = (b >= 7) ? p7 : pb;
    return b * SUBCAP + (u - pb);
}

// ---------------- K3: layer-1 aggregation, wave/node, 8 gathers in flight ----------------
__global__ void k_agg1_h(const int* __restrict__ cnt, const unsigned short* __restrict__ esrc,
                         const float* __restrict__ als, const float* __restrict__ ald,
                         const __half* __restrict__ xh1, float* __restrict__ agg1) {
    const int d = blockIdx.x * 4 + (threadIdx.x >> 6);
    const int lane = threadIdx.x & 63;
    if (d >= N_NODES) return;
    const int hq = lane >> 4;
    const int he = lane & 3;
    const float adh = ald[d * 4 + he];
    const int4 c0 = *(const int4*)(cnt + d * SUBBINS);
    const int4 c1 = *(const int4*)(cnt + d * SUBBINS + 4);
    const int p1 = c0.x, p2 = p1 + c0.y, p3 = p2 + c0.z, p4 = p3 + c0.w;
    const int p5 = p4 + c1.x, p6 = p5 + c1.y, p7 = p6 + c1.z, p8 = p7 + c1.w;
    const int total = p8 + 1;   // + self loop
    const unsigned short* erow = esrc + (size_t)d * ROWSLOT;
    float acc0 = 0.f, acc1 = 0.f, acc2 = 0.f, acc3 = 0.f;
    float denp = 0.f;
    const size_t lby = (size_t)(lane << 3);
    for (int t0 = 0; t0 < total; t0 += 16) {
        int m = total - t0; if (m > 16) m = 16;
        const int slot = lane >> 2;
        float ev = 0.f; int s = d;
        if (slot < m) {
            const int t = t0 + slot;
            if (t > 0) s = erow[bin_slot(t - 1, p1, p2, p3, p4, p5, p6, p7)];
            ev = expf(lrelu(als[s * 4 + he] + adh));
        }
        denp += ev;
        int j = 0;
        for (; j + 8 <= m; j += 8) {
            int ss[8]; float cc[8]; float2 rr[8];
#pragma unroll
            for (int u = 0; u < 8; u++) ss[u] = __shfl(s, (j + u) * 4);
#pragma unroll
            for (int u = 0; u < 8; u++)
                rr[u] = *(const float2*)((const char*)xh1 + ((size_t)ss[u] << 9) + lby);
#pragma unroll
            for (int u = 0; u < 8; u++) cc[u] = __shfl(ev, (j + u) * 4 + hq);
#pragma unroll
            for (int u = 0; u < 8; u++) {
                const float2 a = __half22float2(*(const __half2*)&rr[u].x);
                const float2 b = __half22float2(*(const __half2*)&rr[u].y);
                acc0 += cc[u] * a.x; acc1 += cc[u] * a.y;
                acc2 += cc[u] * b.x; acc3 += cc[u] * b.y;
            }
        }
        for (; j + 4 <= m; j += 4) {
            int ss[4]; float cc[4]; float2 rr[4];
#pragma unroll
            for (int u = 0; u < 4; u++) ss[u] = __shfl(s, (j + u) * 4);
#pragma unroll
            for (int u = 0; u < 4; u++)
                rr[u] = *(const float2*)((const char*)xh1 + ((size_t)ss[u] << 9) + lby);
#pragma unroll
            for (int u = 0; u < 4; u++) cc[u] = __shfl(ev, (j + u) * 4 + hq);
#pragma unroll
            for (int u = 0; u < 4; u++) {
                const float2 a = __half22float2(*(const __half2*)&rr[u].x);
                const float2 b = __half22float2(*(const __half2*)&rr[u].y);
                acc0 += cc[u] * a.x; acc1 += cc[u] * a.y;
                acc2 += cc[u] * b.x; acc3 += cc[u] * b.y;
            }
        }
        for (; j < m; j++) {
            const float cf = __shfl(ev, j * 4 + hq);
            const int sj   = __shfl(s, j * 4);
            const float2 raw = *(const float2*)((const char*)xh1 + ((size_t)sj << 9) + lby);
            const float2 a = __half22float2(*(const __half2*)&raw.x);
            const float2 b = __half22float2(*(const __half2*)&raw.y);
            acc0 += cf * a.x; acc1 += cf * a.y; acc2 += cf * b.x; acc3 += cf * b.y;
        }
    }
    denp += __shfl_xor(denp, 4);
    denp += __shfl_xor(denp, 8);
    denp += __shfl_xor(denp, 16);
    denp += __shfl_xor(denp, 32);
    const float deninv = 1.f / __shfl(denp, hq);
    acc0 *= deninv; acc1 *= deninv; acc2 *= deninv; acc3 *= deninv;
    acc0 += __shfl_xor(acc0, 16); acc0 += __shfl_xor(acc0, 32);
    acc1 += __shfl_xor(acc1, 16); acc1 += __shfl_xor(acc1, 32);
    acc2 += __shfl_xor(acc2, 16); acc2 += __shfl_xor(acc2, 32);
    acc3 += __shfl_xor(acc3, 16); acc3 += __shfl_xor(acc3, 32);
    if (lane < 16) {
        float4 st = { 0.25f * acc0, 0.25f * acc1, 0.25f * acc2, 0.25f * acc3 };
        *(float4*)(agg1 + (size_t)d * HID + lane * 4) = st;
    }
}

// ---------------- K5: xh2h = half(relu(agg1+b1) @ W2) via MFMA + fused als2/ald2 ----------------
__global__ void k_gemm2_mfma(const float* __restrict__ agg1, const float* __restrict__ b1,
                             const __half* __restrict__ w2t, const float* __restrict__ as2,
                             const float* __restrict__ ad2, __half* __restrict__ xh2,
                             float* __restrict__ als, float* __restrict__ ald) {
    __shared__ _Float16 ash[64][72];
    __shared__ _Float16 wsh[128][72];
    const int tid = threadIdx.x;
    const int m0 = blockIdx.x * 64;
#pragma unroll
    for (int i = 0; i < 4; i++) {
        const int f = tid + i * 256;
        const int r = f >> 4;
        const int k4 = (f & 15) * 4;
        const int gr = (m0 + r < N_NODES) ? (m0 + r) : (N_NODES - 1);
        float4 v = *(const float4*)(agg1 + (size_t)gr * HID + k4);
        v.x += b1[k4 + 0]; v.y += b1[k4 + 1];
        v.z += b1[k4 + 2]; v.w += b1[k4 + 3];
        v.x = v.x > 0.f ? v.x : 0.f;
        v.y = v.y > 0.f ? v.y : 0.f;
        v.z = v.z > 0.f ? v.z : 0.f;
        v.w = v.w > 0.f ? v.w : 0.f;
        half4v hv = { (_Float16)v.x, (_Float16)v.y, (_Float16)v.z, (_Float16)v.w };
        *(half4v*)&ash[r][k4] = hv;
    }
#pragma unroll
    for (int i = 0; i < 4; i++) {
        const int u = tid + i * 256;
        const int r = u >> 3;
        const int k = (u & 7) * 8;
        *(half8v*)&wsh[r][k] = *(const half8v*)(w2t + (size_t)r * HID + k);
    }
    __syncthreads();
    const int w = tid >> 6, l = tid & 63;
    const int lr = l & 15, lk = (l >> 4) * 8;
    float4v acc[8];
#pragma unroll
    for (int c = 0; c < 8; c++) acc[c] = (float4v){0.f, 0.f, 0.f, 0.f};
#pragma unroll
    for (int k0 = 0; k0 < HID; k0 += 32) {
        const half8v a = *(const half8v*)&ash[w * 16 + lr][k0 + lk];
#pragma unroll
        for (int c = 0; c < 8; c++) {
            const half8v b = *(const half8v*)&wsh[c * 16 + lr][k0 + lk];
            acc[c] = __builtin_amdgcn_mfma_f32_16x16x32_f16(a, b, acc[c], 0, 0, 0);
        }
    }
    const int rbase = m0 + w * 16 + (l >> 4) * 4;
#pragma unroll
    for (int r = 0; r < 4; r++) {
        const int node = rbase + r;
        if (node < N_NODES) {
            __half* p = xh2 + (size_t)node * (HEADS * HID2) + lr;
#pragma unroll
            for (int c = 0; c < 8; c++) p[c * 16] = __float2half(acc[c][r]);
        }
    }
    float av[8], dv[8];
#pragma unroll
    for (int c = 0; c < 8; c++) {
        const int hh = c >> 1, cih = lr + 16 * (c & 1);
        av[c] = as2[hh * HID2 + cih];
        dv[c] = ad2[hh * HID2 + cih];
    }
#pragma unroll
    for (int r = 0; r < 4; r++) {
        float ps0 = acc[0][r] * av[0] + acc[1][r] * av[1];
        float ps1 = acc[2][r] * av[2] + acc[3][r] * av[3];
        float ps2 = acc[4][r] * av[4] + acc[5][r] * av[5];
        float ps3 = acc[6][r] * av[6] + acc[7][r] * av[7];
        float pd0 = acc[0][r] * dv[0] + acc[1][r] * dv[1];
        float pd1 = acc[2][r] * dv[2] + acc[3][r] * dv[3];
        float pd2 = acc[4][r] * dv[4] + acc[5][r] * dv[5];
        float pd3 = acc[6][r] * dv[6] + acc[7][r] * dv[7];
#pragma unroll
        for (int off = 1; off <= 8; off <<= 1) {
            ps0 += __shfl_xor(ps0, off); ps1 += __shfl_xor(ps1, off);
            ps2 += __shfl_xor(ps2, off); ps3 += __shfl_xor(ps3, off);
            pd0 += __shfl_xor(pd0, off); pd1 += __shfl_xor(pd1, off);
            pd2 += __shfl_xor(pd2, off); pd3 += __shfl_xor(pd3, off);
        }
        if (lr == 0) {
            const int node = rbase + r;
            if (node < N_NODES) {
                float4 sv = { ps0, ps1, ps2, ps3 };
                float4 dvv = { pd0, pd1, pd2, pd3 };
                *(float4*)(als + (size_t)node * HEADS) = sv;
                *(float4*)(ald + (size_t)node * HEADS) = dvv;
            }
        }
    }
}

// ---------------- K7: layer-2 aggregation + fused final projections ----------------
__global__ void k_agg2_final(const int* __restrict__ cnt, const unsigned short* __restrict__ esrc,
                             const float* __restrict__ als, const float* __restrict__ ald,
                             const __half* __restrict__ xh2, const float* __restrict__ b2,
                             const float* __restrict__ Wmu, const float* __restrict__ bmu,
                             const float* __restrict__ Wlv, const float* __restrict__ blv,
                             float* __restrict__ out) {
    const int d = blockIdx.x * 4 + (threadIdx.x >> 6);
    const int lane = threadIdx.x & 63;
    if (d >= N_NODES) return;
    const int hq = lane >> 4;
    const int he = lane & 3;
    const float adh = ald[d * 4 + he];
    const int4 c0 = *(const int4*)(cnt + d * SUBBINS);
    const int4 c1 = *(const int4*)(cnt + d * SUBBINS + 4);
    const int p1 = c0.x, p2 = p1 + c0.y, p3 = p2 + c0.z, p4 = p3 + c0.w;
    const int p5 = p4 + c1.x, p6 = p5 + c1.y, p7 = p6 + c1.z, p8 = p7 + c1.w;
    const int total = p8 + 1;   // + self loop
    const unsigned short* erow = esrc + (size_t)d * ROWSLOT;
    float acc0 = 0.f, acc1 = 0.f;
    float denp = 0.f;
    const size_t lby = (size_t)(lane << 2);
    for (int t0 = 0; t0 < total; t0 += 16) {
        int m = total - t0; if (m > 16) m = 16;
        const int slot = lane >> 2;
        float ev = 0.f; int s = d;
        if (slot < m) {
            const int t = t0 + slot;
            if (t > 0) s = erow[bin_slot(t - 1, p1, p2, p3, p4, p5, p6, p7)];
            ev = expf(lrelu(als[s * 4 + he] + adh));
        }
        denp += ev;
        int j = 0;
        for (; j + 8 <= m; j += 8) {
            int ss[8]; float cc[8]; __half2 rr[8];
#pragma unroll
            for (int u = 0; u < 8; u++) ss[u] = __shfl(s, (j + u) * 4);
#pragma unroll
            for (int u = 0; u < 8; u++)
                rr[u] = *(const __half2*)((const char*)xh2 + ((size_t)ss[u] << 8) + lby);
#pragma unroll
            for (int u = 0; u < 8; u++) cc[u] = __shfl(ev, (j + u) * 4 + hq);
#pragma unroll
            for (int u = 0; u < 8; u++) {
                const float2 xv = __half22float2(rr[u]);
                acc0 += cc[u] * xv.x; acc1 += cc[u] * xv.y;
            }
        }
        for (; j + 4 <= m; j += 4) {
            int ss[4]; float cc[4]; __half2 rr[4];
#pragma unroll
            for (int u = 0; u < 4; u++) ss[u] = __shfl(s, (j + u) * 4);
#pragma unroll
            for (int u = 0; u < 4; u++)
                rr[u] = *(const __half2*)((const char*)xh2 + ((size_t)ss[u] << 8) + lby);
#pragma unroll
            for (int u = 0; u < 4; u++) cc[u] = __shfl(ev, (j + u) * 4 + hq);
#pragma unroll
            for (int u = 0; u < 4; u++) {
                const float2 xv = __half22float2(rr[u]);
                acc0 += cc[u] * xv.x; acc1 += cc[u] * xv.y;
            }
        }
        for (; j < m; j++) {
            const float cf = __shfl(ev, j * 4 + hq);
            const int sj   = __shfl(s, j * 4);
            const __half2 hv = *(const __half2*)((const char*)xh2 + ((size_t)sj << 8) + lby);
            const float2 xv = __half22float2(hv);
            acc0 += cf * xv.x; acc1 += cf * xv.y;
        }
    }
    denp += __shfl_xor(denp, 4);
    denp += __shfl_xor(denp, 8);
    denp += __shfl_xor(denp, 16);
    denp += __shfl_xor(denp, 32);
    const float deninv = 1.f / __shfl(denp, hq);
    acc0 *= deninv; acc1 *= deninv;
    acc0 += __shfl_xor(acc0, 16); acc0 += __shfl_xor(acc0, 32);
    acc1 += __shfl_xor(acc1, 16); acc1 += __shfl_xor(acc1, 32);
    const int cp = lane & 15;
    float h0 = 0.25f * acc0 + b2[2 * cp];
    float h1 = 0.25f * acc1 + b2[2 * cp + 1];
    h0 = h0 > 0.f ? h0 : 0.f;
    h1 = h1 > 0.f ? h1 : 0.f;
    const int jj = lane & 31;
    const bool lv = lane >= 32;
    const float* Wp = lv ? Wlv : Wmu;
    const float* bp = lv ? blv : bmu;
    float o = bp[jj];
#pragma unroll
    for (int k = 0; k < 16; k++) {
        const float e0 = __shfl(h0, k);
        const float e1 = __shfl(h1, k);
        o += e0 * Wp[(2 * k) * LATENT + jj] + e1 * Wp[(2 * k + 1) * LATENT + jj];
    }
    out[(lv ? (size_t)N_NODES * LATENT : (size_t)0) + (size_t)d * LATENT + jj] = o;
}

extern "C" void kernel_launch(void* const* d_in, const int* in_sizes, int n_in,
                              void* d_out, int out_size, void* d_ws, size_t ws_size,
                              hipStream_t stream) {
    const float* x    = (const float*)d_in[0];
    const int*   ei   = (const int*)d_in[1];
    const float* W1   = (const float*)d_in[2];
    const float* as1  = (const float*)d_in[3];
    const float* ad1  = (const float*)d_in[4];
    const float* b1   = (const float*)d_in[5];
    const float* W2   = (const float*)d_in[6];
    const float* as2  = (const float*)d_in[7];
    const float* ad2  = (const float*)d_in[8];
    const float* b2   = (const float*)d_in[9];
    const float* Wmu  = (const float*)d_in[10];
    const float* bmu  = (const float*)d_in[11];
    const float* Wlv  = (const float*)d_in[12];
    const float* blv  = (const float*)d_in[13];
    float* out = (float*)d_out;
    float* ws  = (float*)d_ws;

    __half* xh1h = (__half*)(ws + OFF_XH1H);
    __half* xh2h = (__half*)(ws + OFF_XH2H);
    __half* w1th = (__half*)(ws + OFF_W1TH);
    __half* w2th = (__half*)(ws + OFF_W2TH);
    float* als1 = ws + OFF_ALS1;
    float* ald1 = ws + OFF_ALD1;
    float* agg1 = ws + OFF_AGG1;
    float* als2 = ws + OFF_ALS2;
    float* ald2 = ws + OFF_ALD2;
    int* cur  = (int*)(ws + OFF_CUR);
    unsigned short* esrc = (unsigned short*)(ws + OFF_ESRC);

    k_prep<<<160 + NB_ZERO, 256, 0, stream>>>(W1, W2, w1th, w2th, cur);

    // hybrid dispatch: edge-binning blocks first, GEMM1 blocks fill in behind
    k_gemm1_mfma<<<NBIN + GB1, 256, 0, stream>>>(x, w1th, as1, ad1, xh1h,
                                                 als1, ald1, ei, cur, esrc);

    k_agg1_h<<<(N_NODES + 3) / 4, 256, 0, stream>>>(cur, esrc, als1, ald1, xh1h, agg1);

    k_gemm2_mfma<<<(N_NODES + 63) / 64, 256, 0, stream>>>(agg1, b1, w2th, as2, ad2,
                                                          xh2h, als2, ald2);

    k_agg2_final<<<(N_NODES + 3) / 4, 256, 0, stream>>>(cur, esrc, als2, ald2, xh2h,
                                                        b2, Wmu, bmu, Wlv, blv, out);
}

// Round 13
// 164.595 us; speedup vs baseline: 1.2954x; 1.2954x over previous
//
#include <hip/hip_runtime.h>
#include <hip/hip_fp16.h>

#define N_NODES 50000
#define N_EDGES 800000
#define IN_DIM  128
#define HID     64
#define HID2    32
#define HEADS   4
#define LATENT  32
#define NEG_SLOPE 0.2f

#define NBKT    196        // ceil(50000/256) dst-range buckets
#define BKT_CAP 5120       // mean 4096, sigma ~64 -> +16 sigma
#define EPB_A   4096       // edges per pass-A block
#define PA_BLK  ((N_EDGES + EPB_A - 1) / EPB_A)   // 196
#define GB1     ((N_NODES + 63) / 64)             // 782 gemm1 blocks

typedef _Float16 half8v __attribute__((ext_vector_type(8)));
typedef _Float16 half4v __attribute__((ext_vector_type(4)));
typedef float    float4v __attribute__((ext_vector_type(4)));

// ---------------- workspace layout (float offsets) ----------------
#define OFF_XH1H  ((size_t)0)            //  6,400,000 (half storage)
#define OFF_XH2H  ((size_t)0)            //  3,200,000 (overlay, xh1 dead)
#define OFF_ALS2  ((size_t)8000000)      //    200,000
#define OFF_ALD2  ((size_t)8200000)      //    200,000
#define OFF_AGG1  ((size_t)8400000)      //  3,200,000
#define OFF_ALS1  ((size_t)11600000)     //    200,000
#define OFF_ALD1  ((size_t)11800000)     //    200,000
#define OFF_CNT   ((size_t)12000000)     //     50,000 ints
#define OFF_GCUR  ((size_t)12050000)     //        256 ints
#define OFF_BKT   ((size_t)12050256)     //  1,003,520 ints (196 x 5120)
#define OFF_ESRC  ((size_t)13053776)     //  1,600,000 floats (50k x 64 ushort)
#define OFF_W1TH  ((size_t)14653776)     //     16,384 float slots
#define OFF_W2TH  ((size_t)14670160)     //      4,096 float slots
// total 14,674,256 floats = 58.7 MB

__device__ __forceinline__ float lrelu(float v) {
    return v > 0.f ? v : NEG_SLOPE * v;
}

// ---------------- K0: weight fp16 transposes + bucket-cursor zeroing ----------------
__global__ void k_prep(const float* __restrict__ W1, const float* __restrict__ W2,
                       __half* __restrict__ w1t, __half* __restrict__ w2t,
                       int* __restrict__ gcur) {
    if (blockIdx.x < 160) {
        const int t = blockIdx.x * 256 + threadIdx.x;
        if (t < 32768) {
            const int k = t >> 8, n = t & 255;
            w1t[n * IN_DIM + k] = __float2half(W1[t]);
        } else {
            const int t2 = t - 32768;
            const int k = t2 >> 7, n = t2 & 127;
            w2t[n * HID + k] = __float2half(W2[t2]);
        }
    } else {
        if (threadIdx.x < NBKT) gcur[threadIdx.x] = 0;
    }
}

// ---------------- K1 (hybrid dispatch):
//   blocks [0, PA_BLK):        pass A — partition edges into dst-range buckets
//   blocks [PA_BLK, +GB1):     xh1h = half(x @ W1) MFMA + fused als1/ald1
__global__ void k_gemm1_mfma(const float* __restrict__ x, const __half* __restrict__ w1t,
                             const float* __restrict__ as1, const float* __restrict__ ad1,
                             __half* __restrict__ xh1, float* __restrict__ als,
                             float* __restrict__ ald, const int* __restrict__ ei,
                             int* __restrict__ gcur, int* __restrict__ bktbuf) {
    __shared__ _Float16 xsh[64][136];
    __shared__ _Float16 wsh[64][136];
    __shared__ int lhist[NBKT];
    __shared__ int lbase[NBKT];
    const int tid = threadIdx.x;
    if (blockIdx.x < PA_BLK) {
        // ---- pass A: LDS histogram -> block reservation -> bucketed write ----
        const int e0 = blockIdx.x * EPB_A;
        if (tid < NBKT) lhist[tid] = 0;
        __syncthreads();
        int ofs[16];
#pragma unroll
        for (int r = 0; r < 16; r++) {
            const int e = e0 + r * 256 + tid;
            ofs[r] = -1;
            if (e < N_EDGES) {
                const int dd = ei[N_EDGES + e];
                ofs[r] = atomicAdd(&lhist[dd >> 8], 1);
            }
        }
        __syncthreads();
        if (tid < NBKT) lbase[tid] = atomicAdd(&gcur[tid], lhist[tid]);
        __syncthreads();
#pragma unroll
        for (int r = 0; r < 16; r++) {
            const int e = e0 + r * 256 + tid;
            if (e < N_EDGES) {
                const int s = ei[e], dd = ei[N_EDGES + e];
                const int bkt = dd >> 8;
                const int slot = lbase[bkt] + ofs[r];
                if (slot < BKT_CAP)
                    bktbuf[bkt * BKT_CAP + slot] = (s << 8) | (dd & 255);
            }
        }
        return;
    }
    const int m0 = (blockIdx.x - PA_BLK) * 64;
#pragma unroll
    for (int i = 0; i < 8; i++) {
        const int f = tid + i * 256;
        const int r = f >> 5;
        const int k = (f & 31) * 4;
        const int gr = (m0 + r < N_NODES) ? (m0 + r) : (N_NODES - 1);
        const float4 xv = *(const float4*)(x + (size_t)gr * IN_DIM + k);
        half4v hv = { (_Float16)xv.x, (_Float16)xv.y, (_Float16)xv.z, (_Float16)xv.w };
        *(half4v*)&xsh[r][k] = hv;
    }
    const int w = tid >> 6, l = tid & 63;
    const int lr = l & 15;
    const int lk = (l >> 4) * 8;
    const int rbase = m0 + w * 16 + (l >> 4) * 4;
    for (int nb = 0; nb < 4; nb++) {
        const int n0 = nb * 64;
        __syncthreads();
#pragma unroll
        for (int i = 0; i < 4; i++) {
            const int u = tid + i * 256;
            const int r = u >> 4;
            const int k = (u & 15) * 8;
            *(half8v*)&wsh[r][k] = *(const half8v*)(w1t + (size_t)(n0 + r) * IN_DIM + k);
        }
        __syncthreads();
        float4v acc0 = {0.f,0.f,0.f,0.f}, acc1 = {0.f,0.f,0.f,0.f};
        float4v acc2 = {0.f,0.f,0.f,0.f}, acc3 = {0.f,0.f,0.f,0.f};
#pragma unroll
        for (int k0 = 0; k0 < IN_DIM; k0 += 32) {
            const half8v a  = *(const half8v*)&xsh[w * 16 + lr][k0 + lk];
            const half8v b0 = *(const half8v*)&wsh[ 0 + lr][k0 + lk];
            const half8v b1 = *(const half8v*)&wsh[16 + lr][k0 + lk];
            const half8v b2 = *(const half8v*)&wsh[32 + lr][k0 + lk];
            const half8v b3 = *(const half8v*)&wsh[48 + lr][k0 + lk];
            acc0 = __builtin_amdgcn_mfma_f32_16x16x32_f16(a, b0, acc0, 0, 0, 0);
            acc1 = __builtin_amdgcn_mfma_f32_16x16x32_f16(a, b1, acc1, 0, 0, 0);
            acc2 = __builtin_amdgcn_mfma_f32_16x16x32_f16(a, b2, acc2, 0, 0, 0);
            acc3 = __builtin_amdgcn_mfma_f32_16x16x32_f16(a, b3, acc3, 0, 0, 0);
        }
        const int cbase = n0 + lr;
#pragma unroll
        for (int r = 0; r < 4; r++) {
            const int node = rbase + r;
            if (node < N_NODES) {
                __half* p = xh1 + (size_t)node * (HEADS * HID) + cbase;
                p[0]  = __float2half(acc0[r]);
                p[16] = __float2half(acc1[r]);
                p[32] = __float2half(acc2[r]);
                p[48] = __float2half(acc3[r]);
            }
        }
        const int h = nb;
        const float a0 = as1[(h << 6) + lr +  0], a1 = as1[(h << 6) + lr + 16];
        const float a2 = as1[(h << 6) + lr + 32], a3 = as1[(h << 6) + lr + 48];
        const float d0 = ad1[(h << 6) + lr +  0], d1 = ad1[(h << 6) + lr + 16];
        const float d2 = ad1[(h << 6) + lr + 32], d3 = ad1[(h << 6) + lr + 48];
#pragma unroll
        for (int r = 0; r < 4; r++) {
            float ps = acc0[r] * a0 + acc1[r] * a1 + acc2[r] * a2 + acc3[r] * a3;
            float pd = acc0[r] * d0 + acc1[r] * d1 + acc2[r] * d2 + acc3[r] * d3;
            ps += __shfl_xor(ps, 1); pd += __shfl_xor(pd, 1);
            ps += __shfl_xor(ps, 2); pd += __shfl_xor(pd, 2);
            ps += __shfl_xor(ps, 4); pd += __shfl_xor(pd, 4);
            ps += __shfl_xor(ps, 8); pd += __shfl_xor(pd, 8);
            if (lr == 0) {
                const int node = rbase + r;
                if (node < N_NODES) {
                    als[node * HEADS + h] = ps;
                    ald[node * HEADS + h] = pd;
                }
            }
        }
    }
}

// ---------------- K2: pass B — LDS-local binning per bucket, coalesced write-out ----------------
__global__ void k_passB(const int* __restrict__ bktbuf, const int* __restrict__ gcur,
                        unsigned short* __restrict__ esrc, int* __restrict__ cnt) {
    __shared__ unsigned short lbins[256 * 64];   // 32 KB
    __shared__ int lcur[256];
    const int b = blockIdx.x;
    const int tid = threadIdx.x;
    lcur[tid] = 0;
    __syncthreads();
    int n = gcur[b]; if (n > BKT_CAP) n = BKT_CAP;
    const int* bb = bktbuf + b * BKT_CAP;
    for (int i = tid; i < n; i += 256) {
        const int pk = bb[i];
        const int dlow = pk & 255;
        const int pos = atomicAdd(&lcur[dlow], 1);
        if (pos < 64) lbins[(dlow << 6) + pos] = (unsigned short)(pk >> 8);
    }
    __syncthreads();
    const int node0 = b * 256;
    const int validNodes = (N_NODES - node0 < 256) ? (N_NODES - node0) : 256;
    // coalesced write-out: validNodes * 64 ushort = validNodes * 8 int4
    const int4* src4 = (const int4*)lbins;
    int4* dst4 = (int4*)(esrc + ((size_t)node0 << 6));
    const int n4 = validNodes * 8;
    for (int i = tid; i < n4; i += 256) dst4[i] = src4[i];
    if (tid < validNodes) {
        int c = lcur[tid]; if (c > 64) c = 64;
        cnt[node0 + tid] = c;
    }
}

// ---------------- K3: layer-1 aggregation, wave/node, 8 gathers in flight ----------------
__global__ void k_agg1_h(const int* __restrict__ cnt, const unsigned short* __restrict__ esrc,
                         const float* __restrict__ als, const float* __restrict__ ald,
                         const __half* __restrict__ xh1, float* __restrict__ agg1) {
    const int d = blockIdx.x * 4 + (threadIdx.x >> 6);
    const int lane = threadIdx.x & 63;
    if (d >= N_NODES) return;
    const int hq = lane >> 4;
    const int he = lane & 3;
    const float adh = ald[d * 4 + he];
    const unsigned short* erow = esrc + ((size_t)d << 6);
    const int total = cnt[d] + 1;   // + self loop
    float acc0 = 0.f, acc1 = 0.f, acc2 = 0.f, acc3 = 0.f;
    float denp = 0.f;
    const size_t lby = (size_t)(lane << 3);
    for (int t0 = 0; t0 < total; t0 += 16) {
        int m = total - t0; if (m > 16) m = 16;
        const int slot = lane >> 2;
        float ev = 0.f; int s = d;
        if (slot < m) {
            const int t = t0 + slot;
            if (t > 0) s = erow[t - 1];
            ev = expf(lrelu(als[s * 4 + he] + adh));
        }
        denp += ev;
        int j = 0;
        for (; j + 8 <= m; j += 8) {
            int ss[8]; float cc[8]; float2 rr[8];
#pragma unroll
            for (int u = 0; u < 8; u++) ss[u] = __shfl(s, (j + u) * 4);
#pragma unroll
            for (int u = 0; u < 8; u++)
                rr[u] = *(const float2*)((const char*)xh1 + ((size_t)ss[u] << 9) + lby);
#pragma unroll
            for (int u = 0; u < 8; u++) cc[u] = __shfl(ev, (j + u) * 4 + hq);
#pragma unroll
            for (int u = 0; u < 8; u++) {
                const float2 a = __half22float2(*(const __half2*)&rr[u].x);
                const float2 b = __half22float2(*(const __half2*)&rr[u].y);
                acc0 += cc[u] * a.x; acc1 += cc[u] * a.y;
                acc2 += cc[u] * b.x; acc3 += cc[u] * b.y;
            }
        }
        for (; j + 4 <= m; j += 4) {
            int ss[4]; float cc[4]; float2 rr[4];
#pragma unroll
            for (int u = 0; u < 4; u++) ss[u] = __shfl(s, (j + u) * 4);
#pragma unroll
            for (int u = 0; u < 4; u++)
                rr[u] = *(const float2*)((const char*)xh1 + ((size_t)ss[u] << 9) + lby);
#pragma unroll
            for (int u = 0; u < 4; u++) cc[u] = __shfl(ev, (j + u) * 4 + hq);
#pragma unroll
            for (int u = 0; u < 4; u++) {
                const float2 a = __half22float2(*(const __half2*)&rr[u].x);
                const float2 b = __half22float2(*(const __half2*)&rr[u].y);
                acc0 += cc[u] * a.x; acc1 += cc[u] * a.y;
                acc2 += cc[u] * b.x; acc3 += cc[u] * b.y;
            }
        }
        for (; j < m; j++) {
            const float cf = __shfl(ev, j * 4 + hq);
            const int sj   = __shfl(s, j * 4);
            const float2 raw = *(const float2*)((const char*)xh1 + ((size_t)sj << 9) + lby);
            const float2 a = __half22float2(*(const __half2*)&raw.x);
            const float2 b = __half22float2(*(const __half2*)&raw.y);
            acc0 += cf * a.x; acc1 += cf * a.y; acc2 += cf * b.x; acc3 += cf * b.y;
        }
    }
    denp += __shfl_xor(denp, 4);
    denp += __shfl_xor(denp, 8);
    denp += __shfl_xor(denp, 16);
    denp += __shfl_xor(denp, 32);
    const float deninv = 1.f / __shfl(denp, hq);
    acc0 *= deninv; acc1 *= deninv; acc2 *= deninv; acc3 *= deninv;
    acc0 += __shfl_xor(acc0, 16); acc0 += __shfl_xor(acc0, 32);
    acc1 += __shfl_xor(acc1, 16); acc1 += __shfl_xor(acc1, 32);
    acc2 += __shfl_xor(acc2, 16); acc2 += __shfl_xor(acc2, 32);
    acc3 += __shfl_xor(acc3, 16); acc3 += __shfl_xor(acc3, 32);
    if (lane < 16) {
        float4 st = { 0.25f * acc0, 0.25f * acc1, 0.25f * acc2, 0.25f * acc3 };
        *(float4*)(agg1 + (size_t)d * HID + lane * 4) = st;
    }
}

// ---------------- K5: xh2h = half(relu(agg1+b1) @ W2) via MFMA + fused als2/ald2 ----------------
__global__ void k_gemm2_mfma(const float* __restrict__ agg1, const float* __restrict__ b1,
                             const __half* __restrict__ w2t, const float* __restrict__ as2,
                             const float* __restrict__ ad2, __half* __restrict__ xh2,
                             float* __restrict__ als, float* __restrict__ ald) {
    __shared__ _Float16 ash[64][72];
    __shared__ _Float16 wsh[128][72];
    const int tid = threadIdx.x;
    const int m0 = blockIdx.x * 64;
#pragma unroll
    for (int i = 0; i < 4; i++) {
        const int f = tid + i * 256;
        const int r = f >> 4;
        const int k4 = (f & 15) * 4;
        const int gr = (m0 + r < N_NODES) ? (m0 + r) : (N_NODES - 1);
        float4 v = *(const float4*)(agg1 + (size_t)gr * HID + k4);
        v.x += b1[k4 + 0]; v.y += b1[k4 + 1];
        v.z += b1[k4 + 2]; v.w += b1[k4 + 3];
        v.x = v.x > 0.f ? v.x : 0.f;
        v.y = v.y > 0.f ? v.y : 0.f;
        v.z = v.z > 0.f ? v.z : 0.f;
        v.w = v.w > 0.f ? v.w : 0.f;
        half4v hv = { (_Float16)v.x, (_Float16)v.y, (_Float16)v.z, (_Float16)v.w };
        *(half4v*)&ash[r][k4] = hv;
    }
#pragma unroll
    for (int i = 0; i < 4; i++) {
        const int u = tid + i * 256;
        const int r = u >> 3;
        const int k = (u & 7) * 8;
        *(half8v*)&wsh[r][k] = *(const half8v*)(w2t + (size_t)r * HID + k);
    }
    __syncthreads();
    const int w = tid >> 6, l = tid & 63;
    const int lr = l & 15, lk = (l >> 4) * 8;
    float4v acc[8];
#pragma unroll
    for (int c = 0; c < 8; c++) acc[c] = (float4v){0.f, 0.f, 0.f, 0.f};
#pragma unroll
    for (int k0 = 0; k0 < HID; k0 += 32) {
        const half8v a = *(const half8v*)&ash[w * 16 + lr][k0 + lk];
#pragma unroll
        for (int c = 0; c < 8; c++) {
            const half8v b = *(const half8v*)&wsh[c * 16 + lr][k0 + lk];
            acc[c] = __builtin_amdgcn_mfma_f32_16x16x32_f16(a, b, acc[c], 0, 0, 0);
        }
    }
    const int rbase = m0 + w * 16 + (l >> 4) * 4;
#pragma unroll
    for (int r = 0; r < 4; r++) {
        const int node = rbase + r;
        if (node < N_NODES) {
            __half* p = xh2 + (size_t)node * (HEADS * HID2) + lr;
#pragma unroll
            for (int c = 0; c < 8; c++) p[c * 16] = __float2half(acc[c][r]);
        }
    }
    float av[8], dv[8];
#pragma unroll
    for (int c = 0; c < 8; c++) {
        const int hh = c >> 1, cih = lr + 16 * (c & 1);
        av[c] = as2[hh * HID2 + cih];
        dv[c] = ad2[hh * HID2 + cih];
    }
#pragma unroll
    for (int r = 0; r < 4; r++) {
        float ps0 = acc[0][r] * av[0] + acc[1][r] * av[1];
        float ps1 = acc[2][r] * av[2] + acc[3][r] * av[3];
        float ps2 = acc[4][r] * av[4] + acc[5][r] * av[5];
        float ps3 = acc[6][r] * av[6] + acc[7][r] * av[7];
        float pd0 = acc[0][r] * dv[0] + acc[1][r] * dv[1];
        float pd1 = acc[2][r] * dv[2] + acc[3][r] * dv[3];
        float pd2 = acc[4][r] * dv[4] + acc[5][r] * dv[5];
        float pd3 = acc[6][r] * dv[6] + acc[7][r] * dv[7];
#pragma unroll
        for (int off = 1; off <= 8; off <<= 1) {
            ps0 += __shfl_xor(ps0, off); ps1 += __shfl_xor(ps1, off);
            ps2 += __shfl_xor(ps2, off); ps3 += __shfl_xor(ps3, off);
            pd0 += __shfl_xor(pd0, off); pd1 += __shfl_xor(pd1, off);
            pd2 += __shfl_xor(pd2, off); pd3 += __shfl_xor(pd3, off);
        }
        if (lr == 0) {
            const int node = rbase + r;
            if (node < N_NODES) {
                float4 sv = { ps0, ps1, ps2, ps3 };
                float4 dvv = { pd0, pd1, pd2, pd3 };
                *(float4*)(als + (size_t)node * HEADS) = sv;
                *(float4*)(ald + (size_t)node * HEADS) = dvv;
            }
        }
    }
}

// ---------------- K7: layer-2 aggregation + fused final projections ----------------
__global__ void k_agg2_final(const int* __restrict__ cnt, const unsigned short* __restrict__ esrc,
                             const float* __restrict__ als, const float* __restrict__ ald,
                             const __half* __restrict__ xh2, const float* __restrict__ b2,
                             const float* __restrict__ Wmu, const float* __restrict__ bmu,
                             const float* __restrict__ Wlv, const float* __restrict__ blv,
                             float* __restrict__ out) {
    const int d = blockIdx.x * 4 + (threadIdx.x >> 6);
    const int lane = threadIdx.x & 63;
    if (d >= N_NODES) return;
    const int hq = lane >> 4;
    const int he = lane & 3;
    const float adh = ald[d * 4 + he];
    const unsigned short* erow = esrc + ((size_t)d << 6);
    const int total = cnt[d] + 1;   // + self loop
    float acc0 = 0.f, acc1 = 0.f;
    float denp = 0.f;
    const size_t lby = (size_t)(lane << 2);
    for (int t0 = 0; t0 < total; t0 += 16) {
        int m = total - t0; if (m > 16) m = 16;
        const int slot = lane >> 2;
        float ev = 0.f; int s = d;
        if (slot < m) {
            const int t = t0 + slot;
            if (t > 0) s = erow[t - 1];
            ev = expf(lrelu(als[s * 4 + he] + adh));
        }
        denp += ev;
        int j = 0;
        for (; j + 8 <= m; j += 8) {
            int ss[8]; float cc[8]; __half2 rr[8];
#pragma unroll
            for (int u = 0; u < 8; u++) ss[u] = __shfl(s, (j + u) * 4);
#pragma unroll
            for (int u = 0; u < 8; u++)
                rr[u] = *(const __half2*)((const char*)xh2 + ((size_t)ss[u] << 8) + lby);
#pragma unroll
            for (int u = 0; u < 8; u++) cc[u] = __shfl(ev, (j + u) * 4 + hq);
#pragma unroll
            for (int u = 0; u < 8; u++) {
                const float2 xv = __half22float2(rr[u]);
                acc0 += cc[u] * xv.x; acc1 += cc[u] * xv.y;
            }
        }
        for (; j + 4 <= m; j += 4) {
            int ss[4]; float cc[4]; __half2 rr[4];
#pragma unroll
            for (int u = 0; u < 4; u++) ss[u] = __shfl(s, (j + u) * 4);
#pragma unroll
            for (int u = 0; u < 4; u++)
                rr[u] = *(const __half2*)((const char*)xh2 + ((size_t)ss[u] << 8) + lby);
#pragma unroll
            for (int u = 0; u < 4; u++) cc[u] = __shfl(ev, (j + u) * 4 + hq);
#pragma unroll
            for (int u = 0; u < 4; u++) {
                const float2 xv = __half22float2(rr[u]);
                acc0 += cc[u] * xv.x; acc1 += cc[u] * xv.y;
            }
        }
        for (; j < m; j++) {
            const float cf = __shfl(ev, j * 4 + hq);
            const int sj   = __shfl(s, j * 4);
            const __half2 hv = *(const __half2*)((const char*)xh2 + ((size_t)sj << 8) + lby);
            const float2 xv = __half22float2(hv);
            acc0 += cf * xv.x; acc1 += cf * xv.y;
        }
    }
    denp += __shfl_xor(denp, 4);
    denp += __shfl_xor(denp, 8);
    denp += __shfl_xor(denp, 16);
    denp += __shfl_xor(denp, 32);
    const float deninv = 1.f / __shfl(denp, hq);
    acc0 *= deninv; acc1 *= deninv;
    acc0 += __shfl_xor(acc0, 16); acc0 += __shfl_xor(acc0, 32);
    acc1 += __shfl_xor(acc1, 16); acc1 += __shfl_xor(acc1, 32);
    const int cp = lane & 15;
    float h0 = 0.25f * acc0 + b2[2 * cp];
    float h1 = 0.25f * acc1 + b2[2 * cp + 1];
    h0 = h0 > 0.f ? h0 : 0.f;
    h1 = h1 > 0.f ? h1 : 0.f;
    const int jj = lane & 31;
    const bool lv = lane >= 32;
    const float* Wp = lv ? Wlv : Wmu;
    const float* bp = lv ? blv : bmu;
    float o = bp[jj];
#pragma unroll
    for (int k = 0; k < 16; k++) {
        const float e0 = __shfl(h0, k);
        const float e1 = __shfl(h1, k);
        o += e0 * Wp[(2 * k) * LATENT + jj] + e1 * Wp[(2 * k + 1) * LATENT + jj];
    }
    out[(lv ? (size_t)N_NODES * LATENT : (size_t)0) + (size_t)d * LATENT + jj] = o;
}

extern "C" void kernel_launch(void* const* d_in, const int* in_sizes, int n_in,
                              void* d_out, int out_size, void* d_ws, size_t ws_size,
                              hipStream_t stream) {
    const float* x    = (const float*)d_in[0];
    const int*   ei   = (const int*)d_in[1];
    const float* W1   = (const float*)d_in[2];
    const float* as1  = (const float*)d_in[3];
    const float* ad1  = (const float*)d_in[4];
    const float* b1   = (const float*)d_in[5];
    const float* W2   = (const float*)d_in[6];
    const float* as2  = (const float*)d_in[7];
    const float* ad2  = (const float*)d_in[8];
    const float* b2   = (const float*)d_in[9];
    const float* Wmu  = (const float*)d_in[10];
    const float* bmu  = (const float*)d_in[11];
    const float* Wlv  = (const float*)d_in[12];
    const float* blv  = (const float*)d_in[13];
    float* out = (float*)d_out;
    float* ws  = (float*)d_ws;

    __half* xh1h = (__half*)(ws + OFF_XH1H);
    __half* xh2h = (__half*)(ws + OFF_XH2H);
    __half* w1th = (__half*)(ws + OFF_W1TH);
    __half* w2th = (__half*)(ws + OFF_W2TH);
    float* als1 = ws + OFF_ALS1;
    float* ald1 = ws + OFF_ALD1;
    float* agg1 = ws + OFF_AGG1;
    float* als2 = ws + OFF_ALS2;
    float* ald2 = ws + OFF_ALD2;
    int* cnt  = (int*)(ws + OFF_CNT);
    int* gcur = (int*)(ws + OFF_GCUR);
    int* bktbuf = (int*)(ws + OFF_BKT);
    unsigned short* esrc = (unsigned short*)(ws + OFF_ESRC);

    k_prep<<<161, 256, 0, stream>>>(W1, W2, w1th, w2th, gcur);

    // hybrid: pass-A partition blocks first, GEMM1 blocks fill in behind
    k_gemm1_mfma<<<PA_BLK + GB1, 256, 0, stream>>>(x, w1th, as1, ad1, xh1h,
                                                   als1, ald1, ei, gcur, bktbuf);

    k_passB<<<NBKT, 256, 0, stream>>>(bktbuf, gcur, esrc, cnt);

    k_agg1_h<<<(N_NODES + 3) / 4, 256, 0, stream>>>(cnt, esrc, als1, ald1, xh1h, agg1);

    k_gemm2_mfma<<<(N_NODES + 63) / 64, 256, 0, stream>>>(agg1, b1, w2th, as2, ad2,
                                                          xh2h, als2, ald2);

    k_agg2_final<<<(N_NODES + 3) / 4, 256, 0, stream>>>(cnt, esrc, als2, ald2, xh2h,
                                                        b2, Wmu, bmu, Wlv, blv, out);
}